// Round 7
// baseline (162.908 us; speedup 1.0000x reference)
//
#include <hip/hip_runtime.h>
#include <math.h>

#define DK 32
#define OUT_DIM 32

typedef float  f32x4  __attribute__((ext_vector_type(4)));
typedef short  bf16x8 __attribute__((ext_vector_type(8)));

__device__ __forceinline__ unsigned f2bf_rne(float x) {
    unsigned u = __float_as_uint(x);
    return (u + 0x7fffu + ((u >> 16) & 1u)) >> 16;  // round-nearest-even bf16
}

// Fused prep: (a) row_ptr[n] = first edge with dst >= n (boundary detect on
// sorted dst); (b) KV[s][d] = (bf16(V)<<16)|bf16(K) so one 128 B row carries
// both K and V for an edge gather.
__global__ void prep_kernel(const int* __restrict__ dst,
                            const float* __restrict__ K,
                            const float* __restrict__ V,
                            int E, int N,
                            int* __restrict__ row_ptr,
                            unsigned* __restrict__ KV) {
    const int t = blockIdx.x * blockDim.x + threadIdx.x;
    if (t < E) {
        const int cur  = dst[t];
        const int prev = (t == 0) ? -1 : dst[t - 1];
        for (int j = prev + 1; j <= cur; ++j) row_ptr[j] = t;
        if (t == E - 1) {
            for (int j = cur + 1; j <= N; ++j) row_ptr[j] = E;
        }
    }
    if (t < N * DK) {
        KV[t] = (f2bf_rne(V[t]) << 16) | f2bf_rne(K[t]);
    }
}

// Fallback-path row_ptr builder (ws too small for KV).
__global__ void build_row_ptr_kernel(const int* __restrict__ dst, int E, int N,
                                     int* __restrict__ row_ptr) {
    int e = blockIdx.x * blockDim.x + threadIdx.x;
    if (e >= E) return;
    int cur  = dst[e];
    int prev = (e == 0) ? -1 : dst[e - 1];
    for (int j = prev + 1; j <= cur; ++j) row_ptr[j] = e;
    if (e == E - 1) {
        for (int j = cur + 1; j <= N; ++j) row_ptr[j] = E;
    }
}

// One 64-lane wave owns 16 consecutive nodes, processed as 8 PAIRS: both
// nodes' gathers are issued together (4 independent src->KV chains per
// iteration) to double memory-level parallelism. Lane = (g = edge slot 0..7,
// c = dim chunk 0..7); 16 edge slots per node per iteration; dot reduce
// xor(1,2,4); no running max (scores ~ N(0,1/32), exp safe).
// row_ptr[n0..n0+16] preloaded once into lanes 0..16, bounds via v_readlane.
// Epilogue: per node one xor(8) merge -> 4 partials, normalize, bf16-pack to
// LDS; then 8 MFMAs fold the 4-partial reduction + W_o projection:
//   out(16x32) = part(16x[4x32]) @ Wrep([4x32]x32) + b.
__global__ __launch_bounds__(256) void gat_fused_kernel(
    const float* __restrict__ X, const uint4* __restrict__ KV,
    const float* __restrict__ Wo, const float* __restrict__ bo,
    const int* __restrict__ src, const int* __restrict__ row_ptr,
    float* __restrict__ out, int N) {

    // per-wave A-tile: 16 rows x 17 uint4 (pad) -> 16 B-aligned ds_read_b128
    __shared__ uint4 s_part[4][16 * 17];

    const int tid  = threadIdx.x;
    const int wave = tid >> 6;
    const int lane = tid & 63;
    const int g    = lane >> 3;   // edge slot 0..7
    const int c    = lane & 7;    // dim chunk 0..7
    const int quad = lane >> 4;   // MFMA quad 0..3
    const int col  = lane & 15;   // MFMA col / A-row index

    const int n0 = (blockIdx.x * 4 + wave) * 16;
    if (n0 >= N) return;

    // B fragments (W_o as bf16) for the two 16-col output tiles; identical
    // for every K-chunk because W is replicated across partial groups.
    union BF { bf16x8 v; unsigned short u[8]; };
    BF bf0, bf1;
#pragma unroll
    for (int j2 = 0; j2 < 8; ++j2) {
        bf0.u[j2] = (unsigned short)f2bf_rne(Wo[(quad * 8 + j2) * OUT_DIM + col]);
        bf1.u[j2] = (unsigned short)f2bf_rne(Wo[(quad * 8 + j2) * OUT_DIM + 16 + col]);
    }
    const float bias0 = bo[col];
    const float bias1 = bo[16 + col];

    // Preload row_ptr[n0 .. n0+16] into lanes 0..16 (clamped; row_ptr[N]=E).
    const int rp_reg = row_ptr[min(n0 + min(lane, 16), N)];

    const float4* X4 = (const float4*)X;
    unsigned* part32 = (unsigned*)&s_part[wave][0];
    const float scale = 0.03125f;

    for (int i = 0; i < 16; i += 2) {
        // wave-uniform segment bounds via readlane (OOB nodes -> empty: E..E)
        const int beginA = __builtin_amdgcn_readlane(rp_reg, i);
        const int mid    = __builtin_amdgcn_readlane(rp_reg, i + 1);
        const int endB   = __builtin_amdgcn_readlane(rp_reg, i + 2);
        const int endA   = mid, beginB = mid;
        const int nA = n0 + i, nB = n0 + i + 1;

        float4 qA = X4[min(nA, N - 1) * 8 + c];
        float4 qB = X4[min(nB, N - 1) * 8 + c];
        qA.x *= scale; qA.y *= scale; qA.z *= scale; qA.w *= scale;
        qB.x *= scale; qB.y *= scale; qB.z *= scale; qB.w *= scale;

        float  lA = 0.0f, lB = 0.0f;
        float4 aA = make_float4(0.f, 0.f, 0.f, 0.f);
        float4 aB = make_float4(0.f, 0.f, 0.f, 0.f);

        int eA = beginA, eB = beginB;
        while (eA < endA || eB < endB) {           // wave-uniform condition
            const bool actA = eA < endA;
            const bool actB = eB < endB;
            int s0 = 0, s1 = 0, s2 = 0, s3 = 0;
            uint4 A0, A1, B0, B1;
            // issue ALL gathers (4 independent chains) before any compute
            if (actA) {
                s0 = src[min(eA + g,     endA - 1)];
                s1 = src[min(eA + 8 + g, endA - 1)];
            }
            if (actB) {
                s2 = src[min(eB + g,     endB - 1)];
                s3 = src[min(eB + 8 + g, endB - 1)];
            }
            if (actA) { A0 = KV[s0 * 8 + c]; A1 = KV[s1 * 8 + c]; }
            if (actB) { B0 = KV[s2 * 8 + c]; B1 = KV[s3 * 8 + c]; }

            if (actA) {
                float p0 = fmaf(__uint_as_float(A0.x << 16), qA.x,
                           fmaf(__uint_as_float(A0.y << 16), qA.y,
                           fmaf(__uint_as_float(A0.z << 16), qA.z,
                                __uint_as_float(A0.w << 16) * qA.w)));
                float p1 = fmaf(__uint_as_float(A1.x << 16), qA.x,
                           fmaf(__uint_as_float(A1.y << 16), qA.y,
                           fmaf(__uint_as_float(A1.z << 16), qA.z,
                                __uint_as_float(A1.w << 16) * qA.w)));
                p0 += __shfl_xor(p0, 1);  p1 += __shfl_xor(p1, 1);
                p0 += __shfl_xor(p0, 2);  p1 += __shfl_xor(p1, 2);
                p0 += __shfl_xor(p0, 4);  p1 += __shfl_xor(p1, 4);
                const float w0 = (eA + g     < endA) ? __expf(p0) : 0.0f;
                const float w1 = (eA + 8 + g < endA) ? __expf(p1) : 0.0f;
                lA += w0 + w1;
                aA.x = fmaf(w0, __uint_as_float(A0.x & 0xffff0000u), aA.x);
                aA.y = fmaf(w0, __uint_as_float(A0.y & 0xffff0000u), aA.y);
                aA.z = fmaf(w0, __uint_as_float(A0.z & 0xffff0000u), aA.z);
                aA.w = fmaf(w0, __uint_as_float(A0.w & 0xffff0000u), aA.w);
                aA.x = fmaf(w1, __uint_as_float(A1.x & 0xffff0000u), aA.x);
                aA.y = fmaf(w1, __uint_as_float(A1.y & 0xffff0000u), aA.y);
                aA.z = fmaf(w1, __uint_as_float(A1.z & 0xffff0000u), aA.z);
                aA.w = fmaf(w1, __uint_as_float(A1.w & 0xffff0000u), aA.w);
            }
            if (actB) {
                float p2 = fmaf(__uint_as_float(B0.x << 16), qB.x,
                           fmaf(__uint_as_float(B0.y << 16), qB.y,
                           fmaf(__uint_as_float(B0.z << 16), qB.z,
                                __uint_as_float(B0.w << 16) * qB.w)));
                float p3 = fmaf(__uint_as_float(B1.x << 16), qB.x,
                           fmaf(__uint_as_float(B1.y << 16), qB.y,
                           fmaf(__uint_as_float(B1.z << 16), qB.z,
                                __uint_as_float(B1.w << 16) * qB.w)));
                p2 += __shfl_xor(p2, 1);  p3 += __shfl_xor(p3, 1);
                p2 += __shfl_xor(p2, 2);  p3 += __shfl_xor(p3, 2);
                p2 += __shfl_xor(p2, 4);  p3 += __shfl_xor(p3, 4);
                const float w2 = (eB + g     < endB) ? __expf(p2) : 0.0f;
                const float w3 = (eB + 8 + g < endB) ? __expf(p3) : 0.0f;
                lB += w2 + w3;
                aB.x = fmaf(w2, __uint_as_float(B0.x & 0xffff0000u), aB.x);
                aB.y = fmaf(w2, __uint_as_float(B0.y & 0xffff0000u), aB.y);
                aB.z = fmaf(w2, __uint_as_float(B0.z & 0xffff0000u), aB.z);
                aB.w = fmaf(w2, __uint_as_float(B0.w & 0xffff0000u), aB.w);
                aB.x = fmaf(w3, __uint_as_float(B1.x & 0xffff0000u), aB.x);
                aB.y = fmaf(w3, __uint_as_float(B1.y & 0xffff0000u), aB.y);
                aB.z = fmaf(w3, __uint_as_float(B1.z & 0xffff0000u), aB.z);
                aB.w = fmaf(w3, __uint_as_float(B1.w & 0xffff0000u), aB.w);
            }
            eA += 16; eB += 16;
        }

        // per-node reduce: 8 -> 4 partials (xor 8); l fully (xor 8,16,32)
        lA   += __shfl_xor(lA, 8);
        aA.x += __shfl_xor(aA.x, 8);  aA.y += __shfl_xor(aA.y, 8);
        aA.z += __shfl_xor(aA.z, 8);  aA.w += __shfl_xor(aA.w, 8);
        lA += __shfl_xor(lA, 16);  lA += __shfl_xor(lA, 32);

        lB   += __shfl_xor(lB, 8);
        aB.x += __shfl_xor(aB.x, 8);  aB.y += __shfl_xor(aB.y, 8);
        aB.z += __shfl_xor(aB.z, 8);  aB.w += __shfl_xor(aB.w, 8);
        lB += __shfl_xor(lB, 16);  lB += __shfl_xor(lB, 32);

        const float invA = (endA > beginA) ? (1.0f / lA) : 0.0f;
        const float invB = (endB > beginB) ? (1.0f / lB) : 0.0f;
        aA.x *= invA; aA.y *= invA; aA.z *= invA; aA.w *= invA;
        aB.x *= invB; aB.y *= invB; aB.z *= invB; aB.w *= invB;

        if ((g & 1) == 0) {   // even groups hold the pair sums
            const int p = g >> 1;
            int off = i * 68 + p * 16 + c * 2;  // uint32 units
            part32[off]     = f2bf_rne(aA.x) | (f2bf_rne(aA.y) << 16);
            part32[off + 1] = f2bf_rne(aA.z) | (f2bf_rne(aA.w) << 16);
            off += 68;
            part32[off]     = f2bf_rne(aB.x) | (f2bf_rne(aB.y) << 16);
            part32[off + 1] = f2bf_rne(aB.z) | (f2bf_rne(aB.w) << 16);
        }
    }

    // Projection + partial-group reduction in one MFMA chain.
    union AF { uint4 u; bf16x8 v; };
    f32x4 C0 = {bias0, bias0, bias0, bias0};
    f32x4 C1 = {bias1, bias1, bias1, bias1};
#pragma unroll
    for (int cc = 0; cc < 4; ++cc) {
        AF a;
        a.u = s_part[wave][col * 17 + cc * 4 + quad];  // ds_read_b128
        C0 = __builtin_amdgcn_mfma_f32_16x16x32_bf16(a.v, bf0.v, C0, 0, 0, 0);
        C1 = __builtin_amdgcn_mfma_f32_16x16x32_bf16(a.v, bf1.v, C1, 0, 0, 0);
    }

    // C/D layout: col = lane&15, row = quad*4 + reg (verified mapping)
#pragma unroll
    for (int r = 0; r < 4; ++r) {
        const int n = n0 + quad * 4 + r;
        if (n < N) {
            out[n * OUT_DIM + col]      = C0[r];
            out[n * OUT_DIM + 16 + col] = C1[r];
        }
    }
}

// ---- fallback (R4-proven fp32 path, used only if ws too small for KV) ----
__global__ __launch_bounds__(256) void gat_node_f32_kernel(
    const float* __restrict__ X, const float* __restrict__ Km,
    const float* __restrict__ Vm, const float* __restrict__ Wo,
    const float* __restrict__ bo, const int* __restrict__ src,
    const int* __restrict__ row_ptr, float* __restrict__ out, int N) {
    const int tid  = threadIdx.x;
    const int wave = tid >> 6;
    const int lane = tid & 63;
    const int g    = lane >> 3;
    const int c    = lane & 7;
    const int j    = lane & 31;
    const int half = lane >> 5;
    const int n = blockIdx.x * 4 + wave;
    if (n >= N) return;
    const int begin = row_ptr[n];
    const int end   = row_ptr[n + 1];
    const float4* X4 = (const float4*)X;
    const float4* K4 = (const float4*)Km;
    const float4* V4 = (const float4*)Vm;
    const float4 q4 = X4[n * 8 + c];
    float  l   = 0.0f;
    float4 acc = make_float4(0.0f, 0.0f, 0.0f, 0.0f);
    for (int e0 = begin; e0 < end; e0 += 16) {
        const int  ea = e0 + g;
        const int  eb = ea + 8;
        const bool va = ea < end;
        const bool vb = eb < end;
        const int sa = src[min(ea, end - 1)];
        const int sb = src[min(eb, end - 1)];
        const float4 ka  = K4[sa * 8 + c];
        const float4 kb  = K4[sb * 8 + c];
        const float4 vva = V4[sa * 8 + c];
        const float4 vvb = V4[sb * 8 + c];
        float pa = fmaf(ka.x, q4.x, fmaf(ka.y, q4.y, fmaf(ka.z, q4.z, ka.w * q4.w)));
        float pb = fmaf(kb.x, q4.x, fmaf(kb.y, q4.y, fmaf(kb.z, q4.z, kb.w * q4.w)));
        pa += __shfl_xor(pa, 1);  pb += __shfl_xor(pb, 1);
        pa += __shfl_xor(pa, 2);  pb += __shfl_xor(pb, 2);
        pa += __shfl_xor(pa, 4);  pb += __shfl_xor(pb, 4);
        const float wa = va ? __expf(pa * 0.03125f) : 0.0f;
        const float wb = vb ? __expf(pb * 0.03125f) : 0.0f;
        l += wa + wb;
        acc.x = fmaf(wa, vva.x, acc.x);  acc.y = fmaf(wa, vva.y, acc.y);
        acc.z = fmaf(wa, vva.z, acc.z);  acc.w = fmaf(wa, vva.w, acc.w);
        acc.x = fmaf(wb, vvb.x, acc.x);  acc.y = fmaf(wb, vvb.y, acc.y);
        acc.z = fmaf(wb, vvb.z, acc.z);  acc.w = fmaf(wb, vvb.w, acc.w);
    }
#pragma unroll
    for (int m = 8; m <= 32; m <<= 1) {
        l     += __shfl_xor(l, m);
        acc.x += __shfl_xor(acc.x, m);
        acc.y += __shfl_xor(acc.y, m);
        acc.z += __shfl_xor(acc.z, m);
        acc.w += __shfl_xor(acc.w, m);
    }
    const float inv = (end > begin) ? (1.0f / l) : 0.0f;
    float ag[4] = {acc.x, acc.y, acc.z, acc.w};
    float s = 0.0f;
#pragma unroll
    for (int k = 0; k < 32; ++k) {
        const float a = __int_as_float(
            __builtin_amdgcn_readlane(__float_as_int(ag[k & 3]), k >> 2));
        s = fmaf(a, Wo[k * OUT_DIM + j], s);
    }
    if (half == 0) {
        out[n * OUT_DIM + j] = fmaf(s, inv, bo[j]);
    }
}

extern "C" void kernel_launch(void* const* d_in, const int* in_sizes, int n_in,
                              void* d_out, int out_size, void* d_ws, size_t ws_size,
                              hipStream_t stream) {
    const float* X  = (const float*)d_in[0];
    const float* Km = (const float*)d_in[1];
    const float* Vm = (const float*)d_in[2];
    const float* Wo = (const float*)d_in[3];
    const float* bo = (const float*)d_in[4];
    const int* src  = (const int*)d_in[5];
    const int* dst  = (const int*)d_in[6];

    const int N = in_sizes[0] / DK;
    const int E = in_sizes[5];

    int* row_ptr = (int*)d_ws;                              // (N+1) ints
    const size_t kv_off = (((size_t)(N + 1) * 4) + 127) & ~(size_t)127;
    unsigned* KV = (unsigned*)((char*)d_ws + kv_off);       // N*DK uint32
    const size_t need = kv_off + (size_t)N * DK * 4;
    float* out = (float*)d_out;

    const int tb = 256;

    if (ws_size >= need) {
        const int total   = N * DK;
        const int prep_n  = (E > total) ? E : total;
        prep_kernel<<<(prep_n + tb - 1) / tb, tb, 0, stream>>>(dst, Km, Vm, E, N,
                                                               row_ptr, KV);
        const int waves = (N + 15) / 16;                    // 16 nodes per wave
        const int grid  = (waves + 3) / 4;                  // 4 waves per block
        gat_fused_kernel<<<grid, 256, 0, stream>>>(X, (const uint4*)KV, Wo, bo,
                                                   src, row_ptr, out, N);
    } else {
        build_row_ptr_kernel<<<(E + tb - 1) / tb, tb, 0, stream>>>(dst, E, N, row_ptr);
        const int grid = (N + 3) / 4;
        gat_node_f32_kernel<<<grid, 256, 0, stream>>>(X, Km, Vm, Wo, bo,
                                                      src, row_ptr, out, N);
    }
}

// Round 8
// 149.198 us; speedup vs baseline: 1.0919x; 1.0919x over previous
//
#include <hip/hip_runtime.h>
#include <math.h>

#define DK 32
#define OUT_DIM 32
#define SRC_CAP 512

typedef float  f32x4  __attribute__((ext_vector_type(4)));
typedef short  bf16x8 __attribute__((ext_vector_type(8)));

__device__ __forceinline__ unsigned f2bf_rne(float x) {
    unsigned u = __float_as_uint(x);
    return (u + 0x7fffu + ((u >> 16) & 1u)) >> 16;  // round-nearest-even bf16
}

// Fused prep: (a) row_ptr[n] = first edge with dst >= n (boundary detect on
// sorted dst); (b) KV[s][d] = (bf16(V)<<16)|bf16(K) so one 128 B row carries
// both K and V for an edge gather.
__global__ void prep_kernel(const int* __restrict__ dst,
                            const float* __restrict__ K,
                            const float* __restrict__ V,
                            int E, int N,
                            int* __restrict__ row_ptr,
                            unsigned* __restrict__ KV) {
    const int t = blockIdx.x * blockDim.x + threadIdx.x;
    if (t < E) {
        const int cur  = dst[t];
        const int prev = (t == 0) ? -1 : dst[t - 1];
        for (int j = prev + 1; j <= cur; ++j) row_ptr[j] = t;
        if (t == E - 1) {
            for (int j = cur + 1; j <= N; ++j) row_ptr[j] = E;
        }
    }
    if (t < N * DK) {
        KV[t] = (f2bf_rne(V[t]) << 16) | f2bf_rne(K[t]);
    }
}

// Fallback-path row_ptr builder (ws too small for KV).
__global__ void build_row_ptr_kernel(const int* __restrict__ dst, int E, int N,
                                     int* __restrict__ row_ptr) {
    int e = blockIdx.x * blockDim.x + threadIdx.x;
    if (e >= E) return;
    int cur  = dst[e];
    int prev = (e == 0) ? -1 : dst[e - 1];
    for (int j = prev + 1; j <= cur; ++j) row_ptr[j] = e;
    if (e == E - 1) {
        for (int j = cur + 1; j <= N; ++j) row_ptr[j] = E;
    }
}

// One 64-lane wave owns 16 consecutive nodes. Lane = (g = edge slot 0..7,
// c = dim chunk 0..7); 16 edge slots per batch; dot reduce xor(1,2,4); no
// running max (scores ~ N(0,1/32), exp safe).
//
// R8 structure: the wave's 16 segments are CONTIGUOUS in edge space, so
// src[B..End) is preloaded coalesced into per-wave LDS (cap 512; uniform
// fallback to direct global loads if larger). The edge loop is FLAT over
// batches with a 1-deep KV prefetch: the next batch's gathers (indices from
// LDS -> no load dep) are issued before computing the current batch, hiding
// KV latency across node boundaries. All control flow is wave-uniform, all
// loads unconditional (clamped into [B, End) -> always-valid src values;
// invalid slots only masked at the exp).
// Epilogue: per node xor(8) merge -> 4 partials, normalize, bf16-pack to
// LDS; 8 MFMAs fold partial-reduction + W_o projection:
//   out(16x32) = part(16x[4x32]) @ Wrep([4x32]x32) + b.
__global__ __launch_bounds__(256) void gat_fused_kernel(
    const float* __restrict__ X, const uint4* __restrict__ KV,
    const float* __restrict__ Wo, const float* __restrict__ bo,
    const int* __restrict__ src, const int* __restrict__ row_ptr,
    float* __restrict__ out, int N) {

    __shared__ uint4 s_part[4][16 * 17];   // per-wave A-tile (pad -> b128)
    __shared__ int   s_src[4][SRC_CAP];    // per-wave src segment
    __shared__ int   s_rp[4][17];          // per-wave row_ptr slice

    const int tid  = threadIdx.x;
    const int wave = tid >> 6;
    const int lane = tid & 63;
    const int g    = lane >> 3;   // edge slot 0..7
    const int c    = lane & 7;    // dim chunk 0..7
    const int quad = lane >> 4;   // MFMA quad 0..3
    const int col  = lane & 15;   // MFMA col / A-row index

    const int n0 = (blockIdx.x * 4 + wave) * 16;

    // row_ptr slice preload (lanes 0..16). n0>=N waves read row_ptr[N]=E.
    const int rpv = row_ptr[min(n0 + min(lane, 16), N)];
    if (lane <= 16) s_rp[wave][lane] = rpv;
    const int Bv    = __shfl(rpv, 0);
    const int Endv  = __shfl(rpv, 16);
    const int count = Endv - Bv;

    int* srcbuf = s_src[wave];
    if (count > 0 && count <= SRC_CAP) {
        const int iters = (count + 63) >> 6;
        for (int k = 0; k < iters; ++k) {
            const int idx = (k << 6) + lane;
            srcbuf[idx] = src[Bv + min(idx, count - 1)];  // coalesced
        }
    }
    __syncthreads();          // single barrier; all threads reach it
    if (n0 >= N) return;

    // B fragments (W_o as bf16) + bias — needed by every path.
    union BF { bf16x8 v; unsigned short u[8]; };
    BF bf0, bf1;
#pragma unroll
    for (int j2 = 0; j2 < 8; ++j2) {
        bf0.u[j2] = (unsigned short)f2bf_rne(Wo[(quad * 8 + j2) * OUT_DIM + col]);
        bf1.u[j2] = (unsigned short)f2bf_rne(Wo[(quad * 8 + j2) * OUT_DIM + 16 + col]);
    }
    const float bias0 = bo[col];
    const float bias1 = bo[16 + col];

    const float4* X4 = (const float4*)X;
    unsigned* part32 = (unsigned*)&s_part[wave][0];
    const int* rp    = s_rp[wave];
    const float scale = 0.03125f;

    if (count == 0) {
        // all 16 nodes empty -> zero partials; MFMA yields bias-only rows
        const uint4 z = make_uint4(0u, 0u, 0u, 0u);
        for (int t = lane; t < 16 * 17; t += 64) s_part[wave][t] = z;
    } else if (count <= SRC_CAP) {
        // ---------------- pipelined flat batch loop ----------------
        int i   = 0;
        int end = rp[1];
        int e   = Bv;

        float4 q = X4[min(n0, N - 1) * 8 + c];
        q.x *= scale; q.y *= scale; q.z *= scale; q.w *= scale;

        // prologue: fetch + issue batch 0
        int i0 = min(e + g,     Endv - 1) - Bv;
        int i1 = min(e + 8 + g, Endv - 1) - Bv;
        int s0 = srcbuf[i0];
        int s1 = srcbuf[i1];
        uint4 A0 = KV[s0 * 8 + c];
        uint4 A1 = KV[s1 * 8 + c];

        float  l   = 0.0f;
        float4 acc = make_float4(0.f, 0.f, 0.f, 0.f);

        while (true) {
            const bool last = (e + 16 >= end);            // wave-uniform
            const int  e2   = last ? end : (e + 16);      // next batch base
            const int  end2 = last ? rp[min(i + 2, 16)] : end;

            // prefetch NEXT batch (indices from LDS, issue before compute)
            const int j0 = min(e2 + g,     Endv - 1) - Bv;
            const int j1 = min(e2 + 8 + g, Endv - 1) - Bv;
            const int t0 = srcbuf[j0];
            const int t1 = srcbuf[j1];
            const uint4 P0 = KV[t0 * 8 + c];
            const uint4 P1 = KV[t1 * 8 + c];

            float4 qn = q;
            if (last) {                                   // uniform branch
                qn = X4[min(n0 + i + 1, N - 1) * 8 + c];
                qn.x *= scale; qn.y *= scale; qn.z *= scale; qn.w *= scale;
            }

            // ---- compute current batch with A0/A1 vs q ----
            float p0 = fmaf(__uint_as_float(A0.x << 16), q.x,
                       fmaf(__uint_as_float(A0.y << 16), q.y,
                       fmaf(__uint_as_float(A0.z << 16), q.z,
                            __uint_as_float(A0.w << 16) * q.w)));
            float p1 = fmaf(__uint_as_float(A1.x << 16), q.x,
                       fmaf(__uint_as_float(A1.y << 16), q.y,
                       fmaf(__uint_as_float(A1.z << 16), q.z,
                            __uint_as_float(A1.w << 16) * q.w)));
            p0 += __shfl_xor(p0, 1);  p1 += __shfl_xor(p1, 1);
            p0 += __shfl_xor(p0, 2);  p1 += __shfl_xor(p1, 2);
            p0 += __shfl_xor(p0, 4);  p1 += __shfl_xor(p1, 4);

            const float w0 = (e + g     < end) ? __expf(p0) : 0.0f;
            const float w1 = (e + 8 + g < end) ? __expf(p1) : 0.0f;
            l += w0 + w1;

            acc.x = fmaf(w0, __uint_as_float(A0.x & 0xffff0000u), acc.x);
            acc.y = fmaf(w0, __uint_as_float(A0.y & 0xffff0000u), acc.y);
            acc.z = fmaf(w0, __uint_as_float(A0.z & 0xffff0000u), acc.z);
            acc.w = fmaf(w0, __uint_as_float(A0.w & 0xffff0000u), acc.w);
            acc.x = fmaf(w1, __uint_as_float(A1.x & 0xffff0000u), acc.x);
            acc.y = fmaf(w1, __uint_as_float(A1.y & 0xffff0000u), acc.y);
            acc.z = fmaf(w1, __uint_as_float(A1.z & 0xffff0000u), acc.z);
            acc.w = fmaf(w1, __uint_as_float(A1.w & 0xffff0000u), acc.w);

            if (last) {
                // node i done: 8 -> 4 partials; full l reduce
                l     += __shfl_xor(l, 8);
                acc.x += __shfl_xor(acc.x, 8);  acc.y += __shfl_xor(acc.y, 8);
                acc.z += __shfl_xor(acc.z, 8);  acc.w += __shfl_xor(acc.w, 8);
                l += __shfl_xor(l, 16);  l += __shfl_xor(l, 32);

                const float inv = (l > 0.0f) ? (1.0f / l) : 0.0f;
                acc.x *= inv; acc.y *= inv; acc.z *= inv; acc.w *= inv;

                if ((g & 1) == 0) {
                    const int p   = g >> 1;
                    const int off = i * 68 + p * 16 + c * 2;
                    part32[off]     = f2bf_rne(acc.x) | (f2bf_rne(acc.y) << 16);
                    part32[off + 1] = f2bf_rne(acc.z) | (f2bf_rne(acc.w) << 16);
                }
                l = 0.0f;
                acc = make_float4(0.f, 0.f, 0.f, 0.f);
                ++i;
                if (i >= 16) break;
            }
            e = e2; end = end2;
            A0 = P0; A1 = P1; q = qn;
        }
    } else {
        // ---------------- fallback: proven R6 per-node loop ----------------
        for (int i = 0; i < 16; ++i) {
            const int begin = rp[i];
            const int endn  = rp[i + 1];
            float4 q = X4[min(n0 + i, N - 1) * 8 + c];
            q.x *= scale; q.y *= scale; q.z *= scale; q.w *= scale;

            float  l   = 0.0f;
            float4 acc = make_float4(0.f, 0.f, 0.f, 0.f);

            for (int e0 = begin; e0 < endn; e0 += 16) {
                const int sa = src[min(e0 + g,     endn - 1)];
                const int sb = src[min(e0 + 8 + g, endn - 1)];
                const uint4 A = KV[sa * 8 + c];
                const uint4 B = KV[sb * 8 + c];
                float p0 = fmaf(__uint_as_float(A.x << 16), q.x,
                           fmaf(__uint_as_float(A.y << 16), q.y,
                           fmaf(__uint_as_float(A.z << 16), q.z,
                                __uint_as_float(A.w << 16) * q.w)));
                float p1 = fmaf(__uint_as_float(B.x << 16), q.x,
                           fmaf(__uint_as_float(B.y << 16), q.y,
                           fmaf(__uint_as_float(B.z << 16), q.z,
                                __uint_as_float(B.w << 16) * q.w)));
                p0 += __shfl_xor(p0, 1);  p1 += __shfl_xor(p1, 1);
                p0 += __shfl_xor(p0, 2);  p1 += __shfl_xor(p1, 2);
                p0 += __shfl_xor(p0, 4);  p1 += __shfl_xor(p1, 4);
                const float w0 = (e0 + g     < endn) ? __expf(p0) : 0.0f;
                const float w1 = (e0 + 8 + g < endn) ? __expf(p1) : 0.0f;
                l += w0 + w1;
                acc.x = fmaf(w0, __uint_as_float(A.x & 0xffff0000u), acc.x);
                acc.y = fmaf(w0, __uint_as_float(A.y & 0xffff0000u), acc.y);
                acc.z = fmaf(w0, __uint_as_float(A.z & 0xffff0000u), acc.z);
                acc.w = fmaf(w0, __uint_as_float(A.w & 0xffff0000u), acc.w);
                acc.x = fmaf(w1, __uint_as_float(B.x & 0xffff0000u), acc.x);
                acc.y = fmaf(w1, __uint_as_float(B.y & 0xffff0000u), acc.y);
                acc.z = fmaf(w1, __uint_as_float(B.z & 0xffff0000u), acc.z);
                acc.w = fmaf(w1, __uint_as_float(B.w & 0xffff0000u), acc.w);
            }

            l     += __shfl_xor(l, 8);
            acc.x += __shfl_xor(acc.x, 8);  acc.y += __shfl_xor(acc.y, 8);
            acc.z += __shfl_xor(acc.z, 8);  acc.w += __shfl_xor(acc.w, 8);
            l += __shfl_xor(l, 16);  l += __shfl_xor(l, 32);

            const float inv = (l > 0.0f) ? (1.0f / l) : 0.0f;
            acc.x *= inv; acc.y *= inv; acc.z *= inv; acc.w *= inv;

            if ((g & 1) == 0) {
                const int p   = g >> 1;
                const int off = i * 68 + p * 16 + c * 2;
                part32[off]     = f2bf_rne(acc.x) | (f2bf_rne(acc.y) << 16);
                part32[off + 1] = f2bf_rne(acc.z) | (f2bf_rne(acc.w) << 16);
            }
        }
    }

    // ---------------- common MFMA epilogue ----------------
    union AF { uint4 u; bf16x8 v; };
    f32x4 C0 = {bias0, bias0, bias0, bias0};
    f32x4 C1 = {bias1, bias1, bias1, bias1};
#pragma unroll
    for (int cc = 0; cc < 4; ++cc) {
        AF a;
        a.u = s_part[wave][col * 17 + cc * 4 + quad];  // ds_read_b128
        C0 = __builtin_amdgcn_mfma_f32_16x16x32_bf16(a.v, bf0.v, C0, 0, 0, 0);
        C1 = __builtin_amdgcn_mfma_f32_16x16x32_bf16(a.v, bf1.v, C1, 0, 0, 0);
    }
    // C/D layout: col = lane&15, row = quad*4 + reg (verified mapping)
#pragma unroll
    for (int r = 0; r < 4; ++r) {
        const int n = n0 + quad * 4 + r;
        if (n < N) {
            out[n * OUT_DIM + col]      = C0[r];
            out[n * OUT_DIM + 16 + col] = C1[r];
        }
    }
}

// ---- fallback (R4-proven fp32 path, used only if ws too small for KV) ----
__global__ __launch_bounds__(256) void gat_node_f32_kernel(
    const float* __restrict__ X, const float* __restrict__ Km,
    const float* __restrict__ Vm, const float* __restrict__ Wo,
    const float* __restrict__ bo, const int* __restrict__ src,
    const int* __restrict__ row_ptr, float* __restrict__ out, int N) {
    const int tid  = threadIdx.x;
    const int wave = tid >> 6;
    const int lane = tid & 63;
    const int g    = lane >> 3;
    const int c    = lane & 7;
    const int j    = lane & 31;
    const int half = lane >> 5;
    const int n = blockIdx.x * 4 + wave;
    if (n >= N) return;
    const int begin = row_ptr[n];
    const int end   = row_ptr[n + 1];
    const float4* X4 = (const float4*)X;
    const float4* K4 = (const float4*)Km;
    const float4* V4 = (const float4*)Vm;
    const float4 q4 = X4[n * 8 + c];
    float  l   = 0.0f;
    float4 acc = make_float4(0.0f, 0.0f, 0.0f, 0.0f);
    for (int e0 = begin; e0 < end; e0 += 16) {
        const int  ea = e0 + g;
        const int  eb = ea + 8;
        const bool va = ea < end;
        const bool vb = eb < end;
        const int sa = src[min(ea, end - 1)];
        const int sb = src[min(eb, end - 1)];
        const float4 ka  = K4[sa * 8 + c];
        const float4 kb  = K4[sb * 8 + c];
        const float4 vva = V4[sa * 8 + c];
        const float4 vvb = V4[sb * 8 + c];
        float pa = fmaf(ka.x, q4.x, fmaf(ka.y, q4.y, fmaf(ka.z, q4.z, ka.w * q4.w)));
        float pb = fmaf(kb.x, q4.x, fmaf(kb.y, q4.y, fmaf(kb.z, q4.z, kb.w * q4.w)));
        pa += __shfl_xor(pa, 1);  pb += __shfl_xor(pb, 1);
        pa += __shfl_xor(pa, 2);  pb += __shfl_xor(pb, 2);
        pa += __shfl_xor(pa, 4);  pb += __shfl_xor(pb, 4);
        const float wa = va ? __expf(pa * 0.03125f) : 0.0f;
        const float wb = vb ? __expf(pb * 0.03125f) : 0.0f;
        l += wa + wb;
        acc.x = fmaf(wa, vva.x, acc.x);  acc.y = fmaf(wa, vva.y, acc.y);
        acc.z = fmaf(wa, vva.z, acc.z);  acc.w = fmaf(wa, vva.w, acc.w);
        acc.x = fmaf(wb, vvb.x, acc.x);  acc.y = fmaf(wb, vvb.y, acc.y);
        acc.z = fmaf(wb, vvb.z, acc.z);  acc.w = fmaf(wb, vvb.w, acc.w);
    }
#pragma unroll
    for (int m = 8; m <= 32; m <<= 1) {
        l     += __shfl_xor(l, m);
        acc.x += __shfl_xor(acc.x, m);
        acc.y += __shfl_xor(acc.y, m);
        acc.z += __shfl_xor(acc.z, m);
        acc.w += __shfl_xor(acc.w, m);
    }
    const float inv = (end > begin) ? (1.0f / l) : 0.0f;
    float ag[4] = {acc.x, acc.y, acc.z, acc.w};
    float s = 0.0f;
#pragma unroll
    for (int k = 0; k < 32; ++k) {
        const float a = __int_as_float(
            __builtin_amdgcn_readlane(__float_as_int(ag[k & 3]), k >> 2));
        s = fmaf(a, Wo[k * OUT_DIM + j], s);
    }
    if (half == 0) {
        out[n * OUT_DIM + j] = fmaf(s, inv, bo[j]);
    }
}

extern "C" void kernel_launch(void* const* d_in, const int* in_sizes, int n_in,
                              void* d_out, int out_size, void* d_ws, size_t ws_size,
                              hipStream_t stream) {
    const float* X  = (const float*)d_in[0];
    const float* Km = (const float*)d_in[1];
    const float* Vm = (const float*)d_in[2];
    const float* Wo = (const float*)d_in[3];
    const float* bo = (const float*)d_in[4];
    const int* src  = (const int*)d_in[5];
    const int* dst  = (const int*)d_in[6];

    const int N = in_sizes[0] / DK;
    const int E = in_sizes[5];

    int* row_ptr = (int*)d_ws;                              // (N+1) ints
    const size_t kv_off = (((size_t)(N + 1) * 4) + 127) & ~(size_t)127;
    unsigned* KV = (unsigned*)((char*)d_ws + kv_off);       // N*DK uint32
    const size_t need = kv_off + (size_t)N * DK * 4;
    float* out = (float*)d_out;

    const int tb = 256;

    if (ws_size >= need) {
        const int total  = N * DK;
        const int prep_n = (E > total) ? E : total;
        prep_kernel<<<(prep_n + tb - 1) / tb, tb, 0, stream>>>(dst, Km, Vm, E, N,
                                                               row_ptr, KV);
        const int waves = (N + 15) / 16;                    // 16 nodes per wave
        const int grid  = (waves + 3) / 4;                  // 4 waves per block
        gat_fused_kernel<<<grid, 256, 0, stream>>>(X, (const uint4*)KV, Wo, bo,
                                                   src, row_ptr, out, N);
    } else {
        build_row_ptr_kernel<<<(E + tb - 1) / tb, tb, 0, stream>>>(dst, E, N, row_ptr);
        const int grid = (N + 3) / 4;
        gat_node_f32_kernel<<<grid, 256, 0, stream>>>(X, Km, Vm, Wo, bo,
                                                      src, row_ptr, out, N);
    }
}

// Round 9
// 140.804 us; speedup vs baseline: 1.1570x; 1.0596x over previous
//
#include <hip/hip_runtime.h>
#include <math.h>

#define DK 32
#define OUT_DIM 32

typedef float  f32x4  __attribute__((ext_vector_type(4)));
typedef short  bf16x8 __attribute__((ext_vector_type(8)));

__device__ __forceinline__ unsigned f2bf_rne(float x) {
    unsigned u = __float_as_uint(x);
    return (u + 0x7fffu + ((u >> 16) & 1u)) >> 16;  // round-nearest-even bf16
}

// Fused prep: (a) row_ptr[n] = first edge with dst >= n (boundary detect on
// sorted dst); (b) KV[s][d] = (bf16(V)<<16)|bf16(K) so one 128 B row carries
// both K and V for an edge gather.
__global__ void prep_kernel(const int* __restrict__ dst,
                            const float* __restrict__ K,
                            const float* __restrict__ V,
                            int E, int N,
                            int* __restrict__ row_ptr,
                            unsigned* __restrict__ KV) {
    const int t = blockIdx.x * blockDim.x + threadIdx.x;
    if (t < E) {
        const int cur  = dst[t];
        const int prev = (t == 0) ? -1 : dst[t - 1];
        for (int j = prev + 1; j <= cur; ++j) row_ptr[j] = t;
        if (t == E - 1) {
            for (int j = cur + 1; j <= N; ++j) row_ptr[j] = E;
        }
    }
    if (t < N * DK) {
        KV[t] = (f2bf_rne(V[t]) << 16) | f2bf_rne(K[t]);
    }
}

// Fallback-path row_ptr builder (ws too small for KV).
__global__ void build_row_ptr_kernel(const int* __restrict__ dst, int E, int N,
                                     int* __restrict__ row_ptr) {
    int e = blockIdx.x * blockDim.x + threadIdx.x;
    if (e >= E) return;
    int cur  = dst[e];
    int prev = (e == 0) ? -1 : dst[e - 1];
    for (int j = prev + 1; j <= cur; ++j) row_ptr[j] = e;
    if (e == E - 1) {
        for (int j = cur + 1; j <= N; ++j) row_ptr[j] = E;
    }
}

// R9 partition: block = 4 waves = 16 nodes, 4 nodes PER WAVE -> grid 6250
// blocks (24/CU) so ~32 waves/CU are resident and gather latency is hidden
// by TLP (R6-R8 showed intra-wave MLP alone tops out at ~55 us with only
// ~10 waves/CU). Per-wave edge loop = proven R6 shape: lane = (g = edge
// slot 0..7, c = dim chunk 0..7), 16 edge slots per batch, one 128 B KV
// line per edge, dot reduce xor(1,2,4), no running max (scores ~ N(0,1/32),
// exp cannot overflow). Per node: xor(8) merge -> 4 partials, normalize,
// bf16-pack into the block-shared A-tile. One barrier; wave 0 folds the
// 4-partial reduction + W_o projection for all 16 nodes with 8 MFMAs:
//   out(16x32) = part(16x[4x32]) @ Wrep([4x32]x32) + b.
__global__ __launch_bounds__(256) void gat_fused_kernel(
    const float* __restrict__ X, const uint4* __restrict__ KV,
    const float* __restrict__ Wo, const float* __restrict__ bo,
    const int* __restrict__ src, const int* __restrict__ row_ptr,
    float* __restrict__ out, int N) {

    __shared__ uint4 s_part[16 * 17];   // block A-tile, row stride 17 (pad->b128)

    const int tid  = threadIdx.x;
    const int w    = tid >> 6;    // wave 0..3
    const int lane = tid & 63;
    const int g    = lane >> 3;   // edge slot 0..7
    const int c    = lane & 7;    // dim chunk 0..7

    const int n_blk = blockIdx.x * 16;       // block's first node (< N always)
    const int n_w   = n_blk + w * 4;         // wave's first node

    // row_ptr[n_w .. n_w+4] into lanes 0..4 (clamped; row_ptr[N] = E)
    const int rpv = row_ptr[min(n_w + min(lane, 4), N)];

    const float4* X4 = (const float4*)X;
    unsigned* part32 = (unsigned*)s_part;
    const float scale = 0.03125f;

    for (int i = 0; i < 4; ++i) {
        const int begin = __builtin_amdgcn_readlane(rpv, i);
        const int end   = __builtin_amdgcn_readlane(rpv, i + 1);
        const int n     = n_w + i;           // may be >= N in last block

        float4 q = X4[min(n, N - 1) * 8 + c];
        q.x *= scale; q.y *= scale; q.z *= scale; q.w *= scale;

        float  l   = 0.0f;
        float4 acc = make_float4(0.f, 0.f, 0.f, 0.f);

        for (int e0 = begin; e0 < end; e0 += 16) {
            const int sa = src[min(e0 + g,     end - 1)];
            const int sb = src[min(e0 + 8 + g, end - 1)];
            const uint4 A = KV[sa * 8 + c];   // 8 KV rows per wave load
            const uint4 B = KV[sb * 8 + c];

            float p0 = fmaf(__uint_as_float(A.x << 16), q.x,
                       fmaf(__uint_as_float(A.y << 16), q.y,
                       fmaf(__uint_as_float(A.z << 16), q.z,
                            __uint_as_float(A.w << 16) * q.w)));
            float p1 = fmaf(__uint_as_float(B.x << 16), q.x,
                       fmaf(__uint_as_float(B.y << 16), q.y,
                       fmaf(__uint_as_float(B.z << 16), q.z,
                            __uint_as_float(B.w << 16) * q.w)));
            p0 += __shfl_xor(p0, 1);  p1 += __shfl_xor(p1, 1);
            p0 += __shfl_xor(p0, 2);  p1 += __shfl_xor(p1, 2);
            p0 += __shfl_xor(p0, 4);  p1 += __shfl_xor(p1, 4);

            const float w0 = (e0 + g     < end) ? __expf(p0) : 0.0f;
            const float w1 = (e0 + 8 + g < end) ? __expf(p1) : 0.0f;
            l += w0 + w1;

            acc.x = fmaf(w0, __uint_as_float(A.x & 0xffff0000u), acc.x);
            acc.y = fmaf(w0, __uint_as_float(A.y & 0xffff0000u), acc.y);
            acc.z = fmaf(w0, __uint_as_float(A.z & 0xffff0000u), acc.z);
            acc.w = fmaf(w0, __uint_as_float(A.w & 0xffff0000u), acc.w);
            acc.x = fmaf(w1, __uint_as_float(B.x & 0xffff0000u), acc.x);
            acc.y = fmaf(w1, __uint_as_float(B.y & 0xffff0000u), acc.y);
            acc.z = fmaf(w1, __uint_as_float(B.z & 0xffff0000u), acc.z);
            acc.w = fmaf(w1, __uint_as_float(B.w & 0xffff0000u), acc.w);
        }

        // 8 -> 4 partials (xor 8); l needs the full reduction
        l     += __shfl_xor(l, 8);
        acc.x += __shfl_xor(acc.x, 8);  acc.y += __shfl_xor(acc.y, 8);
        acc.z += __shfl_xor(acc.z, 8);  acc.w += __shfl_xor(acc.w, 8);
        l += __shfl_xor(l, 16);  l += __shfl_xor(l, 32);

        const float inv = (end > begin) ? (1.0f / l) : 0.0f;
        acc.x *= inv; acc.y *= inv; acc.z *= inv; acc.w *= inv;

        if ((g & 1) == 0) {                  // even groups hold pair sums
            const int p   = g >> 1;
            const int row = w * 4 + i;
            const int off = row * 68 + p * 16 + c * 2;   // uint32 units
            part32[off]     = f2bf_rne(acc.x) | (f2bf_rne(acc.y) << 16);
            part32[off + 1] = f2bf_rne(acc.z) | (f2bf_rne(acc.w) << 16);
        }
    }

    __syncthreads();

    // wave 0: projection + partial-group reduction for the block's 16 nodes
    if (w == 0) {
        const int quad = lane >> 4;   // 0..3
        const int col  = lane & 15;

        union BF { bf16x8 v; unsigned short u[8]; };
        BF bf0, bf1;
#pragma unroll
        for (int j2 = 0; j2 < 8; ++j2) {
            bf0.u[j2] = (unsigned short)f2bf_rne(Wo[(quad * 8 + j2) * OUT_DIM + col]);
            bf1.u[j2] = (unsigned short)f2bf_rne(Wo[(quad * 8 + j2) * OUT_DIM + 16 + col]);
        }
        const float bias0 = bo[col];
        const float bias1 = bo[16 + col];

        union AF { uint4 u; bf16x8 v; };
        f32x4 C0 = {bias0, bias0, bias0, bias0};
        f32x4 C1 = {bias1, bias1, bias1, bias1};
#pragma unroll
        for (int cc = 0; cc < 4; ++cc) {
            AF a;
            a.u = s_part[col * 17 + cc * 4 + quad];      // ds_read_b128
            C0 = __builtin_amdgcn_mfma_f32_16x16x32_bf16(a.v, bf0.v, C0, 0, 0, 0);
            C1 = __builtin_amdgcn_mfma_f32_16x16x32_bf16(a.v, bf1.v, C1, 0, 0, 0);
        }
        // C/D layout: col = lane&15, row = quad*4 + reg (verified mapping)
#pragma unroll
        for (int r = 0; r < 4; ++r) {
            const int n = n_blk + quad * 4 + r;
            if (n < N) {
                out[n * OUT_DIM + col]      = C0[r];
                out[n * OUT_DIM + 16 + col] = C1[r];
            }
        }
    }
}

// ---- fallback (R4-proven fp32 path, used only if ws too small for KV) ----
__global__ __launch_bounds__(256) void gat_node_f32_kernel(
    const float* __restrict__ X, const float* __restrict__ Km,
    const float* __restrict__ Vm, const float* __restrict__ Wo,
    const float* __restrict__ bo, const int* __restrict__ src,
    const int* __restrict__ row_ptr, float* __restrict__ out, int N) {
    const int tid  = threadIdx.x;
    const int wave = tid >> 6;
    const int lane = tid & 63;
    const int g    = lane >> 3;
    const int c    = lane & 7;
    const int j    = lane & 31;
    const int half = lane >> 5;
    const int n = blockIdx.x * 4 + wave;
    if (n >= N) return;
    const int begin = row_ptr[n];
    const int end   = row_ptr[n + 1];
    const float4* X4 = (const float4*)X;
    const float4* K4 = (const float4*)Km;
    const float4* V4 = (const float4*)Vm;
    const float4 q4 = X4[n * 8 + c];
    float  l   = 0.0f;
    float4 acc = make_float4(0.0f, 0.0f, 0.0f, 0.0f);
    for (int e0 = begin; e0 < end; e0 += 16) {
        const int  ea = e0 + g;
        const int  eb = ea + 8;
        const bool va = ea < end;
        const bool vb = eb < end;
        const int sa = src[min(ea, end - 1)];
        const int sb = src[min(eb, end - 1)];
        const float4 ka  = K4[sa * 8 + c];
        const float4 kb  = K4[sb * 8 + c];
        const float4 vva = V4[sa * 8 + c];
        const float4 vvb = V4[sb * 8 + c];
        float pa = fmaf(ka.x, q4.x, fmaf(ka.y, q4.y, fmaf(ka.z, q4.z, ka.w * q4.w)));
        float pb = fmaf(kb.x, q4.x, fmaf(kb.y, q4.y, fmaf(kb.z, q4.z, kb.w * q4.w)));
        pa += __shfl_xor(pa, 1);  pb += __shfl_xor(pb, 1);
        pa += __shfl_xor(pa, 2);  pb += __shfl_xor(pb, 2);
        pa += __shfl_xor(pa, 4);  pb += __shfl_xor(pb, 4);
        const float wa = va ? __expf(pa * 0.03125f) : 0.0f;
        const float wb = vb ? __expf(pb * 0.03125f) : 0.0f;
        l += wa + wb;
        acc.x = fmaf(wa, vva.x, acc.x);  acc.y = fmaf(wa, vva.y, acc.y);
        acc.z = fmaf(wa, vva.z, acc.z);  acc.w = fmaf(wa, vva.w, acc.w);
        acc.x = fmaf(wb, vvb.x, acc.x);  acc.y = fmaf(wb, vvb.y, acc.y);
        acc.z = fmaf(wb, vvb.z, acc.z);  acc.w = fmaf(wb, vvb.w, acc.w);
    }
#pragma unroll
    for (int m = 8; m <= 32; m <<= 1) {
        l     += __shfl_xor(l, m);
        acc.x += __shfl_xor(acc.x, m);
        acc.y += __shfl_xor(acc.y, m);
        acc.z += __shfl_xor(acc.z, m);
        acc.w += __shfl_xor(acc.w, m);
    }
    const float inv = (end > begin) ? (1.0f / l) : 0.0f;
    float ag[4] = {acc.x, acc.y, acc.z, acc.w};
    float s = 0.0f;
#pragma unroll
    for (int k = 0; k < 32; ++k) {
        const float a = __int_as_float(
            __builtin_amdgcn_readlane(__float_as_int(ag[k & 3]), k >> 2));
        s = fmaf(a, Wo[k * OUT_DIM + j], s);
    }
    if (half == 0) {
        out[n * OUT_DIM + j] = fmaf(s, inv, bo[j]);
    }
}

extern "C" void kernel_launch(void* const* d_in, const int* in_sizes, int n_in,
                              void* d_out, int out_size, void* d_ws, size_t ws_size,
                              hipStream_t stream) {
    const float* X  = (const float*)d_in[0];
    const float* Km = (const float*)d_in[1];
    const float* Vm = (const float*)d_in[2];
    const float* Wo = (const float*)d_in[3];
    const float* bo = (const float*)d_in[4];
    const int* src  = (const int*)d_in[5];
    const int* dst  = (const int*)d_in[6];

    const int N = in_sizes[0] / DK;
    const int E = in_sizes[5];

    int* row_ptr = (int*)d_ws;                              // (N+1) ints
    const size_t kv_off = (((size_t)(N + 1) * 4) + 127) & ~(size_t)127;
    unsigned* KV = (unsigned*)((char*)d_ws + kv_off);       // N*DK uint32
    const size_t need = kv_off + (size_t)N * DK * 4;
    float* out = (float*)d_out;

    const int tb = 256;

    if (ws_size >= need) {
        const int total  = N * DK;
        const int prep_n = (E > total) ? E : total;
        prep_kernel<<<(prep_n + tb - 1) / tb, tb, 0, stream>>>(dst, Km, Vm, E, N,
                                                               row_ptr, KV);
        const int grid = (N + 15) / 16;     // 16 nodes per block, 4 per wave
        gat_fused_kernel<<<grid, 256, 0, stream>>>(X, (const uint4*)KV, Wo, bo,
                                                   src, row_ptr, out, N);
    } else {
        build_row_ptr_kernel<<<(E + tb - 1) / tb, tb, 0, stream>>>(dst, E, N, row_ptr);
        const int grid = (N + 3) / 4;
        gat_node_f32_kernel<<<grid, 256, 0, stream>>>(X, Km, Vm, Wo, bo,
                                                      src, row_ptr, out, N);
    }
}